// Round 9
// baseline (125.816 us; speedup 1.0000x reference)
//
#include <hip/hip_runtime.h>

// 20-qubit feature map, 4 layers (RX·RY per wire + CNOT chain), <Z_i> outputs.
// wire w <-> bit (19-w). CNOT chain == gray perm: new[y] = old[y ^ (y>>1)], folded
// into the next A read (MODE1) or final expectation (FUSE). Layer 1 on |0..0> is a
// product state computed in-register (MODE0).
// R9 = R8 maps verbatim +: (a) packed complex math (ext_vector float2 -> v_pk_fma),
// (b) state loads issued before gate-prep barrier, (c) final reduce fused into
// passB4 via last-block atomic ticket (reduce_out dispatch removed).

#define NW 20

typedef float f2v __attribute__((ext_vector_type(2)));

__device__ __forceinline__ f2v csw(f2v a) { return __builtin_shufflevector(a, a, 1, 0); }

// packed complex multiply: a * u, where ru = {u.re,u.re}, iu = {-u.im, u.im}
__device__ __forceinline__ f2v pcm(f2v a, f2v ru, f2v iu) { return ru*a + iu*csw(a); }

__device__ __forceinline__ f2v shflx2(f2v v, int m) {
    f2v r;
    r.x = __shfl_xor(v.x, m, 64);
    r.y = __shfl_xor(v.y, m, 64);
    return r;
}

// suffix-XOR: bit b of result = XOR_{j>=b} x_j
__device__ __forceinline__ unsigned sfx(unsigned x) {
    x ^= x >> 1; x ^= x >> 2; x ^= x >> 4; x ^= x >> 8; x ^= x >> 16; return x;
}

// plain gate pairing reg-bit A; g = 8 packed entries {r00,i00,r01,i01,r10,i10,r11,i11}
template<int A>
__device__ __forceinline__ void gate4(f2v (&amp)[4], const f2v* g) {
    f2v r00=g[0], i00=g[1], r01=g[2], i01=g[3], r10=g[4], i10=g[5], r11=g[6], i11=g[7];
    #pragma unroll
    for (int r = 0; r < 4; r++)
        if (!(r & (1 << A))) {
            f2v a0 = amp[r], a1 = amp[r | (1 << A)];
            f2v a0s = csw(a0), a1s = csw(a1);
            amp[r]            = r00*a0 + i00*a0s + r01*a1 + i01*a1s;
            amp[r | (1 << A)] = r10*a0 + i10*a0s + r11*a1 + i11*a1s;
        }
}

// butterfly: swap reg-bit A with lane bit LM (R4-verified orientation)
template<int A, int LM>
__device__ __forceinline__ void swap_reg_lane4(f2v (&amp)[4], unsigned lane) {
    bool hb = (lane & (unsigned)LM) != 0u;
    #pragma unroll
    for (int r = 0; r < 4; r++) {
        if (!(r & (1 << A))) {
            f2v lo = amp[r], hi = amp[r | (1 << A)];
            f2v xs = hb ? lo : hi;
            f2v ys = shflx2(xs, LM);
            amp[r]            = hb ? ys : lo;
            amp[r | (1 << A)] = hb ? hi : ys;
        }
    }
}

// per-block packed gate prep: U = RY(x)*RX(x), half-angle h = x/2.
// u00=(cc,ss) u01=(-cs,-cs) u10=(cs,-cs) u11=(cc,-ss); packed {r,i} per entry.
__device__ __forceinline__ void prep_Gp(const float* __restrict__ x, f2v* Gp, unsigned t) {
    if (t < NW) {
        float h = 0.5f * x[t];
        float c = cosf(h), s = sinf(h);
        float cc = c*c, ss = s*s, cs = c*s;
        Gp[t*8+0] = f2v{cc, cc};    Gp[t*8+1] = f2v{-ss, ss};
        Gp[t*8+2] = f2v{-cs, -cs};  Gp[t*8+3] = f2v{cs, -cs};
        Gp[t*8+4] = f2v{cs, cs};    Gp[t*8+5] = f2v{cs, -cs};
        Gp[t*8+6] = f2v{cc, cc};    Gp[t*8+7] = f2v{ss, -ss};
    }
}

// Stage A: gates on bits 0..11 (wires 19..8). Block = logical high byte H.
// MODE 0: product state (layer-1 folded) + zero the ticket. MODE 1: gray-fold read.
template<int MODE>
__global__ __launch_bounds__(1024) void stageA(const float* __restrict__ x,
                                               const float2* __restrict__ src,
                                               float2* __restrict__ dst,
                                               unsigned* __restrict__ ticket) {
    __shared__ f2v lds[4096];
    __shared__ f2v Gp[8*NW];
    const unsigned t = threadIdx.x;
    const unsigned lane = t & 63u, wv = t >> 6;           // wv: 4 bits
    const unsigned w0 = wv & 1u, w1 = (wv >> 1) & 1u, w2 = (wv >> 2) & 1u, w3 = wv >> 3;
    const unsigned H   = blockIdx.x;
    const unsigned Hp  = H ^ (H >> 1);
    const unsigned inj = (H & 1u) << 11;
    const unsigned lb  = (wv << 8) | (lane << 2);         // logical low-12 base
    const unsigned gb  = (lb ^ (lb >> 1)) ^ inj;          // gray12 ^ inj

    if (MODE == 0 && H == 0 && t == 0) *ticket = 0u;      // reset for fused reduce

    float4 q0, q1;
    if (MODE == 1) {                                      // issue loads BEFORE prep
        const float4* q = (const float4*)(src + ((size_t)Hp << 12) + (gb & ~3u));
        q0 = q[0]; q1 = q[1];
    }
    prep_Gp(x, Gp, t);
    __syncthreads();

    f2v amp[4];
    if (MODE == 1) {
        f2v e0 = f2v{q0.x,q0.y}, e1 = f2v{q0.z,q0.w};
        f2v e2 = f2v{q1.x,q1.y}, e3 = f2v{q1.z,q1.w};
        bool s2 = (gb & 2u) != 0u;   // amp[k] = e[(gb&3) ^ gray2(k)], gray2: 0,1,3,2
        amp[0] = s2 ? e2 : e0;
        amp[1] = s2 ? e3 : e1;
        amp[2] = s2 ? e1 : e3;
        amp[3] = s2 ? e0 : e2;
    } else {
        // amp(Y) = prod_b U^{19-b}[z_b][0], z = gray20(Y); column-0 entries packed.
        f2v P = f2v{1.0f, 0.0f};
        #pragma unroll
        for (int b = 12; b <= 19; b++) {
            int w = 19 - b, bit = (int)((Hp >> (b-12)) & 1u);
            P = pcm(P, Gp[w*8 + bit*4], Gp[w*8 + bit*4 + 1]);
        }
        #pragma unroll
        for (int b = 2; b <= 11; b++) {
            int w = 19 - b, bit = (int)((gb >> b) & 1u);
            P = pcm(P, Gp[w*8 + bit*4], Gp[w*8 + bit*4 + 1]);
        }
        f2v T[4];
        #pragma unroll
        for (int j = 0; j < 4; j++) {
            f2v v = pcm(P, Gp[19*8 + (j&1)*4], Gp[19*8 + (j&1)*4 + 1]);
            T[j]  = pcm(v, Gp[18*8 + ((j>>1)&1)*4], Gp[18*8 + ((j>>1)&1)*4 + 1]);
        }
        bool s2 = (gb & 2u) != 0u;
        amp[0] = s2 ? T[2] : T[0];
        amp[1] = s2 ? T[3] : T[1];
        amp[2] = s2 ? T[1] : T[3];
        amp[3] = s2 ? T[0] : T[2];
    }

    gate4<0>(amp, Gp + 19*8);   // b0
    gate4<1>(amp, Gp + 18*8);   // b1
    swap_reg_lane4<0,1>(amp, lane);    // b0<->b2
    swap_reg_lane4<1,2>(amp, lane);    // b1<->b3
    gate4<0>(amp, Gp + 17*8);   // b2
    gate4<1>(amp, Gp + 16*8);   // b3
    swap_reg_lane4<0,4>(amp, lane);
    swap_reg_lane4<1,8>(amp, lane);
    gate4<0>(amp, Gp + 15*8);   // b4
    gate4<1>(amp, Gp + 14*8);   // b5
    swap_reg_lane4<0,16>(amp, lane);
    swap_reg_lane4<1,32>(amp, lane);
    gate4<0>(amp, Gp + 13*8);   // b6
    gate4<1>(amp, Gp + 12*8);   // b7
    // map: l=b0..5, regs={b6,b7}, wv=b8..11
    #pragma unroll
    for (int k = 0; k < 4; k++) lds[lane | ((unsigned)k << 6) | (wv << 8)] = amp[k];
    __syncthreads();
    // read: regs={b8,b9}; w0,w1 keep b6,b7; w2,w3 = b10,b11
    #pragma unroll
    for (int k = 0; k < 4; k++)
        amp[k] = lds[lane | (w0 << 6) | (w1 << 7) | ((unsigned)k << 8) | (w2 << 10) | (w3 << 11)];
    gate4<0>(amp, Gp + 11*8);   // b8
    gate4<1>(amp, Gp + 10*8);   // b9
    __syncthreads();
    #pragma unroll
    for (int k = 0; k < 4; k++) lds[lane | ((unsigned)k << 6) | (wv << 8)] = amp[k];
    __syncthreads();
    // read: regs={b10,b11}; w0,w1 keep b6,b7 (a8,a9); w2,w3 = b8,b9 (a6,a7)
    #pragma unroll
    for (int k = 0; k < 4; k++)
        amp[k] = lds[lane | (w2 << 6) | (w3 << 7) | (w0 << 8) | (w1 << 9) | ((unsigned)k << 10)];
    gate4<0>(amp, Gp + 9*8);    // b10
    gate4<1>(amp, Gp + 8*8);    // b11
    // store logical: Y = lane | b6,b7(w0,w1) | b8,b9(w2,w3) | b10,b11(k)
    f2v* d = (f2v*)dst + ((size_t)H << 12);
    #pragma unroll
    for (int k = 0; k < 4; k++)
        d[lane | (w0 << 6) | (w1 << 7) | (w2 << 8) | (w3 << 9) | ((unsigned)k << 10)] = amp[k];
}

// Stage B: gates on bits 12..19 (h = high byte); in-place; block = bits 4..11 (bb);
// m = lane&15 = bits 0..3 (128B runs). FUSE=1: fold last gray perm, expectation,
// and final cross-block reduction via atomic ticket (last block writes out).
template<int FUSE>
__global__ __launch_bounds__(1024) void stageB(const float* __restrict__ x,
                                               float2* __restrict__ st,
                                               float* __restrict__ partial,
                                               float* __restrict__ out,
                                               unsigned* __restrict__ ticket) {
    __shared__ f2v lds[4096];
    __shared__ f2v Gp[8*NW];
    __shared__ unsigned islast;
    const unsigned t = threadIdx.x;
    const unsigned lane = t & 63u, wv = t >> 6;
    const unsigned w0 = wv & 1u, w1 = (wv >> 1) & 1u, w2 = (wv >> 2) & 1u, w3 = wv >> 3;
    const unsigned bb = blockIdx.x;
    const unsigned m = lane & 15u, l4 = (lane >> 4) & 1u, l5 = lane >> 5;

    // issue loads BEFORE prep: h = k(h0,h1) | l4(h2) | l5(h3) | wv(h4..7)
    f2v amp[4];
    f2v* stv = (f2v*)st;
    #pragma unroll
    for (int k = 0; k < 4; k++) {
        unsigned h = (unsigned)k | (l4 << 2) | (l5 << 3) | (wv << 4);
        amp[k] = stv[((size_t)h << 12) | (bb << 4) | m];
    }
    prep_Gp(x, Gp, t);
    __syncthreads();

    gate4<0>(amp, Gp + 7*8);    // h0 (b12, wire 7)
    gate4<1>(amp, Gp + 6*8);    // h1 (b13)
    swap_reg_lane4<0,16>(amp, lane);   // h0<->h2
    swap_reg_lane4<1,32>(amp, lane);   // h1<->h3
    gate4<0>(amp, Gp + 5*8);    // h2 (b14)
    gate4<1>(amp, Gp + 4*8);    // h3 (b15)
    // map: l4=h0, l5=h1, regs={h2,h3}, wv=h4..7
    #pragma unroll
    for (int k = 0; k < 4; k++) lds[lane | ((unsigned)k << 6) | (wv << 8)] = amp[k];
    __syncthreads();
    // read: regs={h4,h5}; w0,w1 = h2,h3; w2,w3 = h6,h7
    #pragma unroll
    for (int k = 0; k < 4; k++)
        amp[k] = lds[lane | (w0 << 6) | (w1 << 7) | ((unsigned)k << 8) | (w2 << 10) | (w3 << 11)];
    gate4<0>(amp, Gp + 3*8);    // h4 (b16)
    gate4<1>(amp, Gp + 2*8);    // h5 (b17)
    __syncthreads();
    #pragma unroll
    for (int k = 0; k < 4; k++) lds[lane | ((unsigned)k << 6) | (wv << 8)] = amp[k];
    __syncthreads();
    // read: regs={h6,h7}; w0,w1 keep h2,h3 (a8,a9); w2,w3 = h4,h5 (a6,a7)
    #pragma unroll
    for (int k = 0; k < 4; k++)
        amp[k] = lds[lane | (w2 << 6) | (w3 << 7) | (w0 << 8) | (w1 << 9) | ((unsigned)k << 10)];
    gate4<0>(amp, Gp + 1*8);    // h6 (b18)
    gate4<1>(amp, Gp + 0*8);    // h7 (b19)
    // final map: l4=h0, l5=h1, w0=h2, w1=h3, w2=h4, w3=h5, k={h6,h7}

    if (!FUSE) {
        #pragma unroll
        for (int k = 0; k < 4; k++) {
            unsigned h = l4 | (l5 << 1) | (w0 << 2) | (w1 << 3) | (w2 << 4) | (w3 << 5)
                       | (((unsigned)k & 1u) << 6) | (((unsigned)k >> 1) << 7);
            stv[((size_t)h << 12) | (bb << 4) | m] = amp[k];
        }
    } else {
        // y = invgray(Y); k0 = Y18, k1 = Y19.
        float p[4];
        #pragma unroll
        for (int k = 0; k < 4; k++) p[k] = amp[k].x*amp[k].x + amp[k].y*amp[k].y;
        float S19 = (p[0] + p[1]) - (p[2] + p[3]);      // (-1)^{Y19}
        float D   = p[0] - p[1] - p[2] + p[3];          // (-1)^{Y18^Y19}
        unsigned v = m | (bb << 4) | (l4 << 12) | (l5 << 13) | (w0 << 14)
                   | (w1 << 15) | (w2 << 16) | (w3 << 17);   // Y bits 0..17
        unsigned cm = sfx(v);                            // cm_b = XOR_{j=b..17} Y_j
        float acc[NW];
        acc[0] = S19; acc[1] = D;
        #pragma unroll
        for (int w = 2; w < NW; w++)
            acc[w] = ((cm >> (19 - w)) & 1u) ? -D : D;

        __syncthreads();                 // gate LDS reads done; reuse for reduction
        float* red = (float*)lds;
        #pragma unroll
        for (int w = 0; w < NW; w++) {
            float s = acc[w];
            #pragma unroll
            for (int off = 32; off; off >>= 1) s += __shfl_down(s, off, 64);
            if (lane == 0) red[wv*NW + w] = s;
        }
        __syncthreads();
        if (t < NW) {
            float s = 0.0f;
            #pragma unroll
            for (int v16 = 0; v16 < 16; v16++) s += red[v16*NW + (int)t];
            partial[bb*NW + t] = s;
        }
        __threadfence();                 // device-scope: partial visible before ticket
        __syncthreads();
        if (t == 0) islast = (atomicAdd(ticket, 1u) == 255u) ? 1u : 0u;
        __syncthreads();
        if (islast) {                    // uniform branch; last block reduces all
            float vals[NW];
            #pragma unroll
            for (int w = 0; w < NW; w++)
                vals[w] = (t < 256u) ? partial[t*NW + w] : 0.0f;
            #pragma unroll
            for (int w = 0; w < NW; w++) {
                float s = vals[w];
                #pragma unroll
                for (int off = 32; off; off >>= 1) s += __shfl_down(s, off, 64);
                if (lane == 0) red[wv*NW + w] = s;
            }
            __syncthreads();
            if (t < NW) {
                float s = 0.0f;
                #pragma unroll
                for (int v16 = 0; v16 < 16; v16++) s += red[v16*NW + (int)t];
                out[t] = s;
            }
        }
    }
}

extern "C" void kernel_launch(void* const* d_in, const int* in_sizes, int n_in,
                              void* d_out, int out_size, void* d_ws, size_t ws_size,
                              hipStream_t stream) {
    (void)in_sizes; (void)n_in; (void)out_size; (void)ws_size;
    const float* x = (const float*)d_in[0];
    float* out = (float*)d_out;

    char* ws = (char*)d_ws;
    unsigned* ticket = (unsigned*)(ws + 512);
    float*  partial  = (float*)(ws + 1024);                       // 20 KB
    float2* buf0     = (float2*)(ws + 65536);                     // 8 MB
    float2* buf1     = (float2*)(ws + 65536 + (size_t)(8u << 20));// 8 MB

    // layer 1 folded into product state; layer 2:
    stageA<0><<<256, 1024, 0, stream>>>(x, buf1 /*unused*/, buf0, ticket);
    stageB<0><<<256, 1024, 0, stream>>>(x, buf0, nullptr, nullptr, nullptr);
    // layer 3 (perm folded into A read):
    stageA<1><<<256, 1024, 0, stream>>>(x, buf0, buf1, nullptr);
    stageB<0><<<256, 1024, 0, stream>>>(x, buf1, nullptr, nullptr, nullptr);
    // layer 4 (+ fused expectation + fused final reduce, final perm folded):
    stageA<1><<<256, 1024, 0, stream>>>(x, buf1, buf0, nullptr);
    stageB<1><<<256, 1024, 0, stream>>>(x, buf0, partial, out, ticket);
}

// Round 10
// 65.876 us; speedup vs baseline: 1.9099x; 1.9099x over previous
//
#include <hip/hip_runtime.h>

// 20-qubit feature map, 4 layers (RX·RY per wire + CNOT chain), <Z_i> outputs.
// wire w <-> bit (19-w). CNOT chain == gray perm: new[y] = old[y ^ (y>>1)], folded
// into the next A read (MODE1) or final expectation (FUSE). Layer 1 on |0..0> is a
// product state computed in-register (MODE0).
// R10 = R8 dispatch structure (6 gate passes + reduce_out; dispatch boundary is the
// ONLY cheap cross-XCD barrier — ticket/threadfence cost 78us in R9, grid.sync 29us
// each in R7) + R9's packed complex math (v_pk_fma, VGPR 68->24) + loads-before-prep.

#define NW 20

typedef float f2v __attribute__((ext_vector_type(2)));

__device__ __forceinline__ f2v csw(f2v a) { return __builtin_shufflevector(a, a, 1, 0); }

// packed complex multiply: a * u, where ru = {u.re,u.re}, iu = {-u.im, u.im}
__device__ __forceinline__ f2v pcm(f2v a, f2v ru, f2v iu) { return ru*a + iu*csw(a); }

__device__ __forceinline__ f2v shflx2(f2v v, int m) {
    f2v r;
    r.x = __shfl_xor(v.x, m, 64);
    r.y = __shfl_xor(v.y, m, 64);
    return r;
}

// suffix-XOR: bit b of result = XOR_{j>=b} x_j
__device__ __forceinline__ unsigned sfx(unsigned x) {
    x ^= x >> 1; x ^= x >> 2; x ^= x >> 4; x ^= x >> 8; x ^= x >> 16; return x;
}

// plain gate pairing reg-bit A; g = 8 packed entries {r00,i00,r01,i01,r10,i10,r11,i11}
template<int A>
__device__ __forceinline__ void gate4(f2v (&amp)[4], const f2v* g) {
    f2v r00=g[0], i00=g[1], r01=g[2], i01=g[3], r10=g[4], i10=g[5], r11=g[6], i11=g[7];
    #pragma unroll
    for (int r = 0; r < 4; r++)
        if (!(r & (1 << A))) {
            f2v a0 = amp[r], a1 = amp[r | (1 << A)];
            f2v a0s = csw(a0), a1s = csw(a1);
            amp[r]            = r00*a0 + i00*a0s + r01*a1 + i01*a1s;
            amp[r | (1 << A)] = r10*a0 + i10*a0s + r11*a1 + i11*a1s;
        }
}

// butterfly: swap reg-bit A with lane bit LM (R4-verified orientation)
template<int A, int LM>
__device__ __forceinline__ void swap_reg_lane4(f2v (&amp)[4], unsigned lane) {
    bool hb = (lane & (unsigned)LM) != 0u;
    #pragma unroll
    for (int r = 0; r < 4; r++) {
        if (!(r & (1 << A))) {
            f2v lo = amp[r], hi = amp[r | (1 << A)];
            f2v xs = hb ? lo : hi;
            f2v ys = shflx2(xs, LM);
            amp[r]            = hb ? ys : lo;
            amp[r | (1 << A)] = hb ? hi : ys;
        }
    }
}

// per-block packed gate prep: U = RY(x)*RX(x), half-angle h = x/2.
// u00=(cc,ss) u01=(-cs,-cs) u10=(cs,-cs) u11=(cc,-ss); packed {r,i} per entry.
__device__ __forceinline__ void prep_Gp(const float* __restrict__ x, f2v* Gp, unsigned t) {
    if (t < NW) {
        float h = 0.5f * x[t];
        float c = cosf(h), s = sinf(h);
        float cc = c*c, ss = s*s, cs = c*s;
        Gp[t*8+0] = f2v{cc, cc};    Gp[t*8+1] = f2v{-ss, ss};
        Gp[t*8+2] = f2v{-cs, -cs};  Gp[t*8+3] = f2v{cs, -cs};
        Gp[t*8+4] = f2v{cs, cs};    Gp[t*8+5] = f2v{cs, -cs};
        Gp[t*8+6] = f2v{cc, cc};    Gp[t*8+7] = f2v{ss, -ss};
    }
}

// Stage A: gates on bits 0..11 (wires 19..8). Block = logical high byte H.
// MODE 0: product state (layer-1 folded). MODE 1: gray-fold read from src.
template<int MODE>
__global__ __launch_bounds__(1024) void stageA(const float* __restrict__ x,
                                               const float2* __restrict__ src,
                                               float2* __restrict__ dst) {
    __shared__ f2v lds[4096];
    __shared__ f2v Gp[8*NW];
    const unsigned t = threadIdx.x;
    const unsigned lane = t & 63u, wv = t >> 6;           // wv: 4 bits
    const unsigned w0 = wv & 1u, w1 = (wv >> 1) & 1u, w2 = (wv >> 2) & 1u, w3 = wv >> 3;
    const unsigned H   = blockIdx.x;
    const unsigned Hp  = H ^ (H >> 1);
    const unsigned inj = (H & 1u) << 11;
    const unsigned lb  = (wv << 8) | (lane << 2);         // logical low-12 base
    const unsigned gb  = (lb ^ (lb >> 1)) ^ inj;          // gray12 ^ inj

    float4 q0, q1;
    if (MODE == 1) {                                      // issue loads BEFORE prep
        const float4* q = (const float4*)(src + ((size_t)Hp << 12) + (gb & ~3u));
        q0 = q[0]; q1 = q[1];
    }
    prep_Gp(x, Gp, t);
    __syncthreads();

    f2v amp[4];
    if (MODE == 1) {
        f2v e0 = f2v{q0.x,q0.y}, e1 = f2v{q0.z,q0.w};
        f2v e2 = f2v{q1.x,q1.y}, e3 = f2v{q1.z,q1.w};
        bool s2 = (gb & 2u) != 0u;   // amp[k] = e[(gb&3) ^ gray2(k)], gray2: 0,1,3,2
        amp[0] = s2 ? e2 : e0;
        amp[1] = s2 ? e3 : e1;
        amp[2] = s2 ? e1 : e3;
        amp[3] = s2 ? e0 : e2;
    } else {
        // amp(Y) = prod_b U^{19-b}[z_b][0], z = gray20(Y); column-0 entries packed.
        f2v P = f2v{1.0f, 0.0f};
        #pragma unroll
        for (int b = 12; b <= 19; b++) {
            int w = 19 - b, bit = (int)((Hp >> (b-12)) & 1u);
            P = pcm(P, Gp[w*8 + bit*4], Gp[w*8 + bit*4 + 1]);
        }
        #pragma unroll
        for (int b = 2; b <= 11; b++) {
            int w = 19 - b, bit = (int)((gb >> b) & 1u);
            P = pcm(P, Gp[w*8 + bit*4], Gp[w*8 + bit*4 + 1]);
        }
        f2v T[4];
        #pragma unroll
        for (int j = 0; j < 4; j++) {
            f2v v = pcm(P, Gp[19*8 + (j&1)*4], Gp[19*8 + (j&1)*4 + 1]);
            T[j]  = pcm(v, Gp[18*8 + ((j>>1)&1)*4], Gp[18*8 + ((j>>1)&1)*4 + 1]);
        }
        bool s2 = (gb & 2u) != 0u;
        amp[0] = s2 ? T[2] : T[0];
        amp[1] = s2 ? T[3] : T[1];
        amp[2] = s2 ? T[1] : T[3];
        amp[3] = s2 ? T[0] : T[2];
    }

    gate4<0>(amp, Gp + 19*8);   // b0
    gate4<1>(amp, Gp + 18*8);   // b1
    swap_reg_lane4<0,1>(amp, lane);    // b0<->b2
    swap_reg_lane4<1,2>(amp, lane);    // b1<->b3
    gate4<0>(amp, Gp + 17*8);   // b2
    gate4<1>(amp, Gp + 16*8);   // b3
    swap_reg_lane4<0,4>(amp, lane);
    swap_reg_lane4<1,8>(amp, lane);
    gate4<0>(amp, Gp + 15*8);   // b4
    gate4<1>(amp, Gp + 14*8);   // b5
    swap_reg_lane4<0,16>(amp, lane);
    swap_reg_lane4<1,32>(amp, lane);
    gate4<0>(amp, Gp + 13*8);   // b6
    gate4<1>(amp, Gp + 12*8);   // b7
    // map: l=b0..5, regs={b6,b7}, wv=b8..11
    #pragma unroll
    for (int k = 0; k < 4; k++) lds[lane | ((unsigned)k << 6) | (wv << 8)] = amp[k];
    __syncthreads();
    // read: regs={b8,b9}; w0,w1 keep b6,b7; w2,w3 = b10,b11
    #pragma unroll
    for (int k = 0; k < 4; k++)
        amp[k] = lds[lane | (w0 << 6) | (w1 << 7) | ((unsigned)k << 8) | (w2 << 10) | (w3 << 11)];
    gate4<0>(amp, Gp + 11*8);   // b8
    gate4<1>(amp, Gp + 10*8);   // b9
    __syncthreads();
    #pragma unroll
    for (int k = 0; k < 4; k++) lds[lane | ((unsigned)k << 6) | (wv << 8)] = amp[k];
    __syncthreads();
    // read: regs={b10,b11}; w0,w1 keep b6,b7 (a8,a9); w2,w3 = b8,b9 (a6,a7)
    #pragma unroll
    for (int k = 0; k < 4; k++)
        amp[k] = lds[lane | (w2 << 6) | (w3 << 7) | (w0 << 8) | (w1 << 9) | ((unsigned)k << 10)];
    gate4<0>(amp, Gp + 9*8);    // b10
    gate4<1>(amp, Gp + 8*8);    // b11
    // store logical: Y = lane | b6,b7(w0,w1) | b8,b9(w2,w3) | b10,b11(k)
    f2v* d = (f2v*)dst + ((size_t)H << 12);
    #pragma unroll
    for (int k = 0; k < 4; k++)
        d[lane | (w0 << 6) | (w1 << 7) | (w2 << 8) | (w3 << 9) | ((unsigned)k << 10)] = amp[k];
}

// Stage B: gates on bits 12..19 (h = high byte); in-place; block = bits 4..11 (bb);
// m = lane&15 = bits 0..3 (128B runs). FUSE=1: fold last gray perm + expectation
// partials (one row per block; reduced by reduce_out).
template<int FUSE>
__global__ __launch_bounds__(1024) void stageB(const float* __restrict__ x,
                                               float2* __restrict__ st,
                                               float* __restrict__ partial) {
    __shared__ f2v lds[4096];
    __shared__ f2v Gp[8*NW];
    const unsigned t = threadIdx.x;
    const unsigned lane = t & 63u, wv = t >> 6;
    const unsigned w0 = wv & 1u, w1 = (wv >> 1) & 1u, w2 = (wv >> 2) & 1u, w3 = wv >> 3;
    const unsigned bb = blockIdx.x;
    const unsigned m = lane & 15u, l4 = (lane >> 4) & 1u, l5 = lane >> 5;

    // issue loads BEFORE prep: h = k(h0,h1) | l4(h2) | l5(h3) | wv(h4..7)
    f2v amp[4];
    f2v* stv = (f2v*)st;
    #pragma unroll
    for (int k = 0; k < 4; k++) {
        unsigned h = (unsigned)k | (l4 << 2) | (l5 << 3) | (wv << 4);
        amp[k] = stv[((size_t)h << 12) | (bb << 4) | m];
    }
    prep_Gp(x, Gp, t);
    __syncthreads();

    gate4<0>(amp, Gp + 7*8);    // h0 (b12, wire 7)
    gate4<1>(amp, Gp + 6*8);    // h1 (b13)
    swap_reg_lane4<0,16>(amp, lane);   // h0<->h2
    swap_reg_lane4<1,32>(amp, lane);   // h1<->h3
    gate4<0>(amp, Gp + 5*8);    // h2 (b14)
    gate4<1>(amp, Gp + 4*8);    // h3 (b15)
    // map: l4=h0, l5=h1, regs={h2,h3}, wv=h4..7
    #pragma unroll
    for (int k = 0; k < 4; k++) lds[lane | ((unsigned)k << 6) | (wv << 8)] = amp[k];
    __syncthreads();
    // read: regs={h4,h5}; w0,w1 = h2,h3; w2,w3 = h6,h7
    #pragma unroll
    for (int k = 0; k < 4; k++)
        amp[k] = lds[lane | (w0 << 6) | (w1 << 7) | ((unsigned)k << 8) | (w2 << 10) | (w3 << 11)];
    gate4<0>(amp, Gp + 3*8);    // h4 (b16)
    gate4<1>(amp, Gp + 2*8);    // h5 (b17)
    __syncthreads();
    #pragma unroll
    for (int k = 0; k < 4; k++) lds[lane | ((unsigned)k << 6) | (wv << 8)] = amp[k];
    __syncthreads();
    // read: regs={h6,h7}; w0,w1 keep h2,h3 (a8,a9); w2,w3 = h4,h5 (a6,a7)
    #pragma unroll
    for (int k = 0; k < 4; k++)
        amp[k] = lds[lane | (w2 << 6) | (w3 << 7) | (w0 << 8) | (w1 << 9) | ((unsigned)k << 10)];
    gate4<0>(amp, Gp + 1*8);    // h6 (b18)
    gate4<1>(amp, Gp + 0*8);    // h7 (b19)
    // final map: l4=h0, l5=h1, w0=h2, w1=h3, w2=h4, w3=h5, k={h6,h7}

    if (!FUSE) {
        #pragma unroll
        for (int k = 0; k < 4; k++) {
            unsigned h = l4 | (l5 << 1) | (w0 << 2) | (w1 << 3) | (w2 << 4) | (w3 << 5)
                       | (((unsigned)k & 1u) << 6) | (((unsigned)k >> 1) << 7);
            stv[((size_t)h << 12) | (bb << 4) | m] = amp[k];
        }
    } else {
        // y = invgray(Y); k0 = Y18, k1 = Y19.
        float p[4];
        #pragma unroll
        for (int k = 0; k < 4; k++) p[k] = amp[k].x*amp[k].x + amp[k].y*amp[k].y;
        float S19 = (p[0] + p[1]) - (p[2] + p[3]);      // (-1)^{Y19}
        float D   = p[0] - p[1] - p[2] + p[3];          // (-1)^{Y18^Y19}
        unsigned v = m | (bb << 4) | (l4 << 12) | (l5 << 13) | (w0 << 14)
                   | (w1 << 15) | (w2 << 16) | (w3 << 17);   // Y bits 0..17
        unsigned cm = sfx(v);                            // cm_b = XOR_{j=b..17} Y_j
        float acc[NW];
        acc[0] = S19; acc[1] = D;
        #pragma unroll
        for (int w = 2; w < NW; w++)
            acc[w] = ((cm >> (19 - w)) & 1u) ? -D : D;

        __syncthreads();                 // gate LDS reads done; reuse for reduction
        float* red = (float*)lds;
        #pragma unroll
        for (int w = 0; w < NW; w++) {
            float s = acc[w];
            #pragma unroll
            for (int off = 32; off; off >>= 1) s += __shfl_down(s, off, 64);
            if (lane == 0) red[wv*NW + w] = s;
        }
        __syncthreads();
        if (t < NW) {
            float s = 0.0f;
            #pragma unroll
            for (int v16 = 0; v16 < 16; v16++) s += red[v16*NW + (int)t];
            partial[bb*NW + t] = s;
        }
    }
}

__global__ __launch_bounds__(256) void reduce_out(const float* __restrict__ partial,
                                                  float* __restrict__ out) {
    __shared__ float red[4*NW];
    unsigned t = threadIdx.x;
    float vals[NW];
    #pragma unroll
    for (int w = 0; w < NW; w++) vals[w] = partial[t*NW + w];
    #pragma unroll
    for (int w = 0; w < NW; w++) {
        float v = vals[w];
        #pragma unroll
        for (int off = 32; off; off >>= 1) v += __shfl_down(v, off, 64);
        if ((t & 63u) == 0u) red[(t >> 6)*NW + w] = v;
    }
    __syncthreads();
    if (t < NW) out[t] = red[t] + red[NW+t] + red[2*NW+t] + red[3*NW+t];
}

extern "C" void kernel_launch(void* const* d_in, const int* in_sizes, int n_in,
                              void* d_out, int out_size, void* d_ws, size_t ws_size,
                              hipStream_t stream) {
    (void)in_sizes; (void)n_in; (void)out_size; (void)ws_size;
    const float* x = (const float*)d_in[0];
    float* out = (float*)d_out;

    char* ws = (char*)d_ws;
    float*  partial = (float*)(ws + 1024);                        // 20 KB
    float2* buf0    = (float2*)(ws + 65536);                      // 8 MB
    float2* buf1    = (float2*)(ws + 65536 + (size_t)(8u << 20)); // 8 MB

    // layer 1 folded into product state; layer 2:
    stageA<0><<<256, 1024, 0, stream>>>(x, buf1 /*unused*/, buf0);
    stageB<0><<<256, 1024, 0, stream>>>(x, buf0, nullptr);
    // layer 3 (perm folded into A read):
    stageA<1><<<256, 1024, 0, stream>>>(x, buf0, buf1);
    stageB<0><<<256, 1024, 0, stream>>>(x, buf1, nullptr);
    // layer 4 (+ fused expectation, final perm folded):
    stageA<1><<<256, 1024, 0, stream>>>(x, buf1, buf0);
    stageB<1><<<256, 1024, 0, stream>>>(x, buf0, partial);
    reduce_out<<<1, 256, 0, stream>>>(partial, out);
}